// Round 8
// baseline (560.791 us; speedup 1.0000x reference)
//
#include <hip/hip_runtime.h>
#include <hip/hip_fp16.h>

// DKVMN forward, v25 = v24's per-wave LDS-window structure in 512-thread
//  8-wave blocks (one block = one batch PAIR).
//  R7 evidence: stall (~97-99us) is INVARIANT to w delivery (SMEM v19 302,
//  VMEM v20/21 378-381, LDS+barrier v22 334, LDS barrier-free v24 319).
//  Occupancy counters across v17/v19/v24 fit a model of only ~4.8-6.9
//  BLOCKS/CU resident (a workgroup-slot cap, not VGPR/LDS: v17 had LDS=0,
//  VGPR=32, still ~4.8 of 8) -> dispatch runs in 2-3 sequential rounds at
//  ~2.7-4.8 waves/SIMD; VALUBusy 64-69% == resident_waves*334cyc/wall in
//  every variant. Fix: 1024 blocks x 8 waves -> full residency needs only
//  4 blocks/CU. Waves 0-2: heavy roles, batch 2p; waves 3-5: heavy, batch
//  2p+1; waves 6/7: tails. Per-wave code identical to v24 (LDS window, 4
//  coalesced stage loads/group, reg double-buffer prefetch, ea depth-2,
//  zero SMEM / zero barriers in the hot loop). launch_bounds(512,8) caps
//  VGPR at 64 (v24 used 52).
//  Math bit-identical to v18/v19/v24 (same fdot2+hfma2 order, same w bits).
//  k1 prep : EA {-e,a} f16 | Wt/Wh/Q1 | W1s pack | zero outputs 1..3.
//  k3 mlp_pred : MFMA 16x16x32 bf16 GEMM [B*S,224]@[224,64] + fused epilogue.
// Workspace: Wt 1MB | Q1 1MB | EA 8MB | W1s 32KB | Wh 0.64MB | RD 164MB.

#define NQ1   5001
#define NQA   10001
#define MEMN  50
#define KD    50
#define VD    200
#define FC    50
#define BB    2048
#define SS    200
#define EA_R  16
#define WHS   32       // Wh row stride in u32 (25 pairs + 7 zero pad, 128B)

#define EA_B   626     // ceil(10001/16)
#define WQ_B   1251    // ceil(5001/4)
#define PACK_B 8
#define PREP_G (EA_B + WQ_B + PACK_B)   // 1885 blocks

#define WG    8        // steps per window group; 25 groups * 8 = SS exactly

typedef unsigned int   u32;
typedef unsigned short u16;
typedef short    s8v __attribute__((ext_vector_type(8)));   // 8 bf16 (4 VGPRs)
typedef float    f4v __attribute__((ext_vector_type(4)));   // MFMA C/D
typedef _Float16 h2v __attribute__((ext_vector_type(2)));   // packed f16 pair
typedef u32      u4v __attribute__((ext_vector_type(4)));   // dwordx4

__device__ __forceinline__ float fast_sigmoid(float x) { return 1.f / (1.f + __expf(-x)); }
__device__ __forceinline__ float fast_tanh(float x) {
    float e2 = __expf(2.f * x);           // inf-safe
    return 1.f - 2.f / (e2 + 1.f);
}
__device__ __forceinline__ float bfu16_to_f(u16 u) {
    union { float f; u32 i; } x; x.i = ((u32)u) << 16; return x.f;
}
__device__ __forceinline__ u16 f_to_bfu16(float f) {   // RNE, finite inputs
    union { float f; u32 i; } x; x.f = f;
    return (u16)((x.i + 0x7fffu + ((x.i >> 16) & 1u)) >> 16);
}
__device__ __forceinline__ h2v u32_to_h2v(u32 u) {
    union { u32 i; h2v h; } x; x.i = u; return x.h;
}
__device__ __forceinline__ u16 f16bits(float f) {
    union { __half h; u16 u; } x; x.h = __float2half(f); return x.u;
}
__device__ __forceinline__ float h16_to_f(u16 u) {
    union { u16 u; __half h; } x; x.u = u; return __half2float(x.h);
}

// ---- merged prep: EA table | per-q tables | W1 pack | aux-output zeroing ----
__global__ __launch_bounds__(256) void prep(
        const float* __restrict__ qemb, const float* __restrict__ km,
        const float* __restrict__ w1,   const float* __restrict__ b1,
        const float* __restrict__ qaemb,
        const float* __restrict__ ew,   const float* __restrict__ ebias,
        const float* __restrict__ aw,   const float* __restrict__ abias,
        float* __restrict__ Wt, u32* __restrict__ Wh, float* __restrict__ Q1,
        u32* __restrict__ EA, u16* __restrict__ W1s,
        float* __restrict__ out_aux) {
    const int tid = threadIdx.x;
    const int blk = blockIdx.x;

    // every block zeroes its slice of outputs 1..3 (replaces hipMemsetAsync)
    for (size_t i = (size_t)blk * 256 + tid; i < 3ull * BB * SS;
         i += (size_t)PREP_G * 256)
        out_aux[i] = 0.f;

    __shared__ float smem[VD * EA_R];             // 12.8 KB (EA role); WQ uses 256

    if (blk < EA_B) {
        // ---------------- EA role: {-e, a} packed f16 ----------------
        const int r0 = blk * EA_R;
        if (tid < VD) {
            #pragma unroll
            for (int r = 0; r < EA_R; ++r) {
                int row = r0 + r;
                smem[tid * EA_R + r] = (row < NQA) ? qaemb[(size_t)row * VD + tid] : 0.f;
            }
        }
        __syncthreads();
        if (tid >= VD) return;

        float accE[EA_R], accA[EA_R];
        #pragma unroll
        for (int r = 0; r < EA_R; ++r) { accE[r] = 0.f; accA[r] = 0.f; }
        for (int k = 0; k < VD; ++k) {
            float we = ew[k * VD + tid];
            float wa = aw[k * VD + tid];
            #pragma unroll
            for (int r = 0; r < EA_R; ++r) {
                float qv = smem[k * EA_R + r];
                accE[r] = fmaf(qv, we, accE[r]);
                accA[r] = fmaf(qv, wa, accA[r]);
            }
        }
        float be = ebias[tid], ba = abias[tid];
        #pragma unroll
        for (int r = 0; r < EA_R; ++r) {
            int row = r0 + r;
            if (row < NQA) {
                u16 ne16 = f16bits(-fast_sigmoid(accE[r] + be));   // -e
                u16 a16  = f16bits(fast_tanh(accA[r] + ba));       //  a
                EA[(size_t)row * VD + tid] = (u32)ne16 | ((u32)a16 << 16);
            }
        }
    } else if (blk < EA_B + WQ_B) {
        // ---------------- WQ role (== proven build_wq, 4 q/block) ----------------
        const int lane = tid & 63;
        const int wv   = tid >> 6;
        const int q    = (blk - EA_B) * 4 + wv;
        const bool qok = q < NQ1;
        float* qrow = smem + wv * 64;             // 50 used per wave
        if (qok && lane < KD) qrow[lane] = qemb[q * KD + lane];
        __syncthreads();
        if (!qok) return;

        float s = -1e30f;
        if (lane < MEMN) {
            s = 0.f;
            #pragma unroll
            for (int k = 0; k < KD; ++k) s = fmaf(qrow[k], km[lane * KD + k], s);
        }
        float mx = s;
        #pragma unroll
        for (int off = 32; off >= 1; off >>= 1) mx = fmaxf(mx, __shfl_xor(mx, off, 64));
        float e = (lane < MEMN) ? __expf(s - mx) : 0.f;
        float sum = e;
        #pragma unroll
        for (int off = 32; off >= 1; off >>= 1) sum += __shfl_xor(sum, off, 64);
        float wv_ = (lane < MEMN) ? (e / sum) : 0.f;
        if (lane < MEMN) Wt[q * MEMN + lane] = wv_;

        // f16-pair row: lane i<25 packs (w[2i], w[2i+1]); pairs 25..31 zero
        float plo = __shfl(wv_, 2 * (lane & 31), 64);
        float phi = __shfl(wv_, 2 * (lane & 31) + 1, 64);
        if (lane < 25) {
            Wh[q * WHS + lane] = (u32)f16bits(plo) | ((u32)f16bits(phi) << 16);
        } else if (lane < WHS) {
            Wh[q * WHS + lane] = 0;
        }

        if (lane < FC) {
            float h = b1[lane];
            #pragma unroll
            for (int k = 0; k < KD; ++k)
                h = fmaf(qrow[k], w1[(VD + k) * FC + lane], h);
            Q1[q * FC + lane] = h;
        }
    } else {
        // ---------------- pack role (== proven pack_w1) ----------------
        for (int idx = (blk - EA_B - WQ_B) * 256 + tid; idx < 4 * 7 * 64 * 8;
             idx += PACK_B * 256) {
            int j    = idx & 7;
            int lane = (idx >> 3) & 63;
            int kt   = (idx >> 9) % 7;
            int nt   = idx / 3584;
            int k = kt * 32 + ((lane >> 4) << 3) + j;
            int n = nt * 16 + (lane & 15);
            float v = (k < VD && n < FC) ? w1[k * FC + n] : 0.f;
            W1s[idx] = f_to_bfu16(v);
        }
    }
}

// one recurrence step for 64 dense columns; w row in VGPRs (6x b128 + 1)
__device__ __forceinline__ void state_step_v(const u4v (&w)[6], u32 w6, u32 ea,
                                             h2v (&mv)[25], float& rdA, float& rdB) {
    // ea = {-e (lo f16), a (hi f16)}; broadcast halves via v_perm
    h2v nev2 = u32_to_h2v(__builtin_amdgcn_perm(ea, ea, 0x01000100u));
    h2v av2  = u32_to_h2v(__builtin_amdgcn_perm(ea, ea, 0x03020302u));
    rdA = 0.f; rdB = 0.f;
    #pragma unroll
    for (int i = 0; i < 25; i += 2) {        // 13 iters (i=24 single)
        u32 wu0 = (i < 24) ? w[i >> 2][i & 3] : w6;     // compile-time select
        h2v w0 = u32_to_h2v(wu0);
#if __has_builtin(__builtin_amdgcn_fdot2)
        rdA = __builtin_amdgcn_fdot2(w0, mv[i], rdA, false);
#else
        rdA = fmaf((float)w0.x, (float)mv[i].x,
              fmaf((float)w0.y, (float)mv[i].y, rdA));
#endif
        mv[i] = __builtin_elementwise_fma(
            w0, __builtin_elementwise_fma(nev2, mv[i], av2), mv[i]);
        if (i + 1 < 25) {
            h2v w1p = u32_to_h2v(w[(i + 1) >> 2][(i + 1) & 3]);
#if __has_builtin(__builtin_amdgcn_fdot2)
            rdB = __builtin_amdgcn_fdot2(w1p, mv[i + 1], rdB, false);
#else
            rdB = fmaf((float)w1p.x, (float)mv[i + 1].x,
                  fmaf((float)w1p.y, (float)mv[i + 1].y, rdB));
#endif
            mv[i + 1] = __builtin_elementwise_fma(
                w1p, __builtin_elementwise_fma(nev2, mv[i + 1], av2), mv[i + 1]);
        }
    }
}

// ---- recurrence: BB/2 blocks x 512 thr (8 waves) = one batch PAIR/block ----
//  waves 0-2: heavy roles 0-2, batch 2p; waves 3-5: heavy, batch 2p+1;
//  waves 6/7: tail, batch 2p / 2p+1. Per-wave structure == v24:
//  private win[wid][8][32]; per group 4 coalesced VMEM stage loads at s=0,
//  ds_writes at s=7; per step prefetch w(t+1) into alternate reg buffer at
//  step TOP; ea depth-2 per-lane VMEM; zero SMEM / zero barriers in loop.
__global__ __launch_bounds__(512, 8) void dkvmn_state(
        const int* __restrict__ qd, const int* __restrict__ qad,
        const u32* __restrict__ Wh, const u32* __restrict__ EA,
        const float* __restrict__ ivm, u16* __restrict__ READ) {
    const int tid  = threadIdx.x;          // 0..511
    const int lane = tid & 63;
    const int wid  = tid >> 6;             // 0..7
    const int blk  = blockIdx.x;           // 0..BB/2-1

    __shared__ int qsf[2 * SS], qasf[2 * SS];   // 3.2 KB (both batches)
    __shared__ u32 win[6][WG][WHS];             // 6 KB: per-heavy-wave window

    for (int i = tid; i < 2 * SS; i += 512) {
        qsf[i]  = qd[(size_t)blk * 2 * SS + i];
        qasf[i] = qad[(size_t)blk * 2 * SS + i];
    }
    __syncthreads();                        // the ONLY barrier

    if (wid < 6) {
        // ---------------- heavy wave: 64 unique columns ----------------
        const int bat  = (wid >= 3);        // batch within pair
        const int role = wid - bat * 3;     // 0..2
        const int base = (blk * 2 + bat) * SS;
        const int* qp  = qsf  + bat * SS;
        const int* qap = qasf + bat * SS;

        const int v    = role * 64 + lane;  // < 192, every lane unique
        const int word = lane & 31;         // word within Wh row
        const int half = lane >> 5;         // 0,1: row-within-pair

        h2v mv[25];                         // pair i = slots (2i, 2i+1)
        #pragma unroll
        for (int i = 0; i < 25; ++i) {
            mv[i].x = (_Float16)ivm[(2 * i) * VD + v];
            mv[i].y = (_Float16)ivm[(2 * i + 1) * VD + v];
        }

        // ---- prologue: stage group 0, prefetch w(0), init qa/ea pipes ----
        u32 wst[4];
        {
            int qg0[4];
            #pragma unroll
            for (int i = 0; i < 4; ++i) qg0[i] = qp[i * 2 + half];
            #pragma unroll
            for (int i = 0; i < 4; ++i)
                wst[i] = Wh[(size_t)qg0[i] * WHS + word];
            #pragma unroll
            for (int i = 0; i < 4; ++i)
                win[wid][i * 2 + half][word] = wst[i];   // auto vmcnt wait
        }
        int qstage[4];                      // rows for group-1 staging
        #pragma unroll
        for (int i = 0; i < 4; ++i) qstage[i] = qp[WG + i * 2 + half];

        u4v wrb[2][6]; u32 wrb6[2];         // w reg double buffer
        {
            const u32* wp = &win[wid][0][0];
            #pragma unroll
            for (int j = 0; j < 6; ++j) wrb[0][j] = *(const u4v*)(wp + j * 4);
            wrb6[0] = wp[24];
        }

        int qa2 = qap[2], qa3 = qap[3];
        u32 ea_c = EA[(size_t)qap[0] * VD + v];
        u32 ea_n = EA[(size_t)qap[1] * VD + v];

        // ---- main loop: 25 groups x 8 steps, barrier-free ----
        for (int g = 0; g < SS / WG; ++g) {
            #pragma unroll
            for (int s = 0; s < WG; ++s) {
                const int t   = g * WG + s;
                const int cur = s & 1;
                const int nxt = cur ^ 1;

                if (s == 0) {
                    // issue coalesced VMEM stage loads for group g+1
                    #pragma unroll
                    for (int i = 0; i < 4; ++i)
                        wst[i] = Wh[(size_t)qstage[i] * WHS + word];
                }
                if (s == WG - 1) {
                    // write group g+1 into window (7-step vmcnt cover),
                    // BEFORE this step's w prefetch reads slot 0
                    #pragma unroll
                    for (int i = 0; i < 4; ++i)
                        win[wid][i * 2 + half][word] = wst[i];
                    // rows for group g+2 staging (consumed next s==0)
                    #pragma unroll
                    for (int i = 0; i < 4; ++i) {
                        int idx = (g + 2) * WG + i * 2 + half;
                        idx = (idx < SS) ? idx : (SS - 1);
                        qstage[i] = qp[idx];
                    }
                }

                // prefetch w(t+1) into alternate buffer (full-step cover)
                {
                    const u32* wp = &win[wid][(s + 1) & (WG - 1)][0];
                    #pragma unroll
                    for (int j = 0; j < 6; ++j)
                        wrb[nxt][j] = *(const u4v*)(wp + j * 4);
                    wrb6[nxt] = wp[24];
                }

                // ea for t+2 (depth-2, per-lane coalesced)
                u32 ea_f = EA[(size_t)qa2 * VD + v];
                // qa for t+4 (reg pipeline via in-order DS)
                int t4 = t + 4; t4 = (t4 < SS) ? t4 : (SS - 1);
                int qa_nn = qap[t4];

                // consume w(t), ea(t)
                float rdA, rdB;
                state_step_v(wrb[cur], wrb6[cur], ea_c, mv, rdA, rdB);
                READ[(size_t)(base + t) * VD + v] = f_to_bfu16(rdA + rdB);

                qa2 = qa3; qa3 = qa_nn;
                ea_c = ea_n; ea_n = ea_f;
            }
        }
    } else {
        // ---------------- tail wave: v = 192..199, 8 slot-groups ----------------
        const int bat  = wid - 6;
        const int base = (blk * 2 + bat) * SS;
        const int* qp  = qsf  + bat * SS;
        const int* qap = qasf + bat * SS;

        const int v8  = lane & 7;
        const int grp = lane >> 3;         // owns pairs grp*4 .. grp*4+3
        const int v   = 192 + v8;

        h2v mv4[4];
        #pragma unroll
        for (int j = 0; j < 4; ++j) {
            int p = grp * 4 + j;
            if (p < 25) {
                mv4[j].x = (_Float16)ivm[(2 * p) * VD + v];
                mv4[j].y = (_Float16)ivm[(2 * p + 1) * VD + v];
            } else {                       // padded pairs: w=0 keeps them 0
                mv4[j].x = (_Float16)0.f;
                mv4[j].y = (_Float16)0.f;
            }
        }

        int q0 = qp[0], q1 = qp[1];
        u32 ea_c = EA[(size_t)qap[0] * VD + v];
        u32 ea_n = EA[(size_t)qap[1] * VD + v];
        u4v wq_c = *(const u4v*)(Wh + (size_t)q0 * WHS + grp * 4);
        u4v wq_n = *(const u4v*)(Wh + (size_t)q1 * WHS + grp * 4);

        for (int t = 0; t < SS; ++t) {
            int tn = t + 2; tn = (tn < SS) ? tn : (SS - 1);
            int q_nn  = qp[tn];
            int qa_nn = qap[tn];
            u32 ea_nn = EA[(size_t)qa_nn * VD + v];
            u4v wq_nn = *(const u4v*)(Wh + (size_t)q_nn * WHS + grp * 4);

            h2v nev2 = u32_to_h2v(__builtin_amdgcn_perm(ea_c, ea_c, 0x01000100u));
            h2v av2  = u32_to_h2v(__builtin_amdgcn_perm(ea_c, ea_c, 0x03020302u));

            float rd = 0.f;
            #pragma unroll
            for (int j = 0; j < 4; ++j) {
                h2v w2 = u32_to_h2v(wq_c[j]);
#if __has_builtin(__builtin_amdgcn_fdot2)
                rd = __builtin_amdgcn_fdot2(w2, mv4[j], rd, false);
#else
                rd = fmaf((float)w2.x, (float)mv4[j].x,
                     fmaf((float)w2.y, (float)mv4[j].y, rd));
#endif
                mv4[j] = __builtin_elementwise_fma(
                    w2, __builtin_elementwise_fma(nev2, mv4[j], av2), mv4[j]);
            }
            // reduce over the 8 slot-groups (lane stride 8)
            rd += __shfl_xor(rd, 8, 64);
            rd += __shfl_xor(rd, 16, 64);
            rd += __shfl_xor(rd, 32, 64);
            if (grp == 0)
                READ[(size_t)(base + t) * VD + v] = f_to_bfu16(rd);

            ea_c = ea_n; ea_n = ea_nn;
            wq_c = wq_n; wq_n = wq_nn;
        }
    }
}

// ---- prediction MLP via MFMA: per wave one 16-row strip, K=224, N=64 ----
__global__ __launch_bounds__(256) void mlp_pred(
        const u16* __restrict__ RD, const int* __restrict__ qd,
        const float* __restrict__ Q1tab, const u16* __restrict__ W1s,
        const float* __restrict__ w2, const float* __restrict__ b2,
        float* __restrict__ out) {
    const int tid  = threadIdx.x;
    const int lane = tid & 63;
    const int wv   = tid >> 6;
    const int strip = blockIdx.x * 4 + wv;
    const int row0  = strip * 16;

    const int mrow = lane & 15;        // A row within strip / C-D col (feature)
    const int quad = lane >> 4;

    s8v a[7];
    {
        const u16* arow = RD + (size_t)(row0 + mrow) * VD + quad * 8;
        #pragma unroll
        for (int kt = 0; kt < 7; ++kt)
            a[kt] = *(const s8v*)(arow + kt * 32);   // k>=200 garbage * B=0
    }

    const float b2f = b2[0];
    float pf[4] = {0.f, 0.f, 0.f, 0.f};

    #pragma unroll
    for (int nt = 0; nt < 4; ++nt) {
        s8v bfr[7];
        #pragma unroll
        for (int kt = 0; kt < 7; ++kt)
            bfr[kt] = *(const s8v*)(W1s + (((nt * 7 + kt) * 64) + lane) * 8);

        f4v acc = {0.f, 0.f, 0.f, 0.f};
        #pragma unroll
        for (int kt = 0; kt < 7; ++kt)
            acc = __builtin_amdgcn_mfma_f32_16x16x32_bf16(a[kt], bfr[kt], acc, 0, 0, 0);

        const int f = nt * 16 + mrow;                  // output feature col
        const float w2f = (f < FC) ? w2[f] : 0.f;
        #pragma unroll
        for (int r = 0; r < 4; ++r) {
            int row = row0 + quad * 4 + r;
            float h = acc[r] + Q1tab[qd[row] * FC + f];
            pf[r] = fmaf(fast_tanh(h), w2f, pf[r]);
        }
    }

    #pragma unroll
    for (int r = 0; r < 4; ++r) {
        float s = pf[r];
        s += __shfl_xor(s, 1, 64);
        s += __shfl_xor(s, 2, 64);
        s += __shfl_xor(s, 4, 64);
        s += __shfl_xor(s, 8, 64);
        if (mrow == 0)
            out[row0 + quad * 4 + r] = fast_sigmoid(s + b2f);
    }
}

// ---- fallback (barrier version, f32) if workspace too small ----
__global__ void dkvmn_main(const int* __restrict__ qd, const int* __restrict__ qad,
                           const float* __restrict__ Wtab, const float* __restrict__ Q1tab,
                           const u32* __restrict__ EA,
                           const float* __restrict__ ivm,
                           const float* __restrict__ w1,
                           const float* __restrict__ w2,
                           const float* __restrict__ b2,
                           float* __restrict__ out) {
    const int tid  = threadIdx.x;
    const int b    = blockIdx.x;
    const int v    = tid;
    const int lane = tid & 63;
    const int wv   = tid >> 6;

    __shared__ alignas(16) float read_lds[4 * 52];
    __shared__ alignas(16) float part_lds[4 * 52];

    float mv[MEMN];
    if (v < VD) {
        #pragma unroll
        for (int m = 0; m < MEMN; ++m) mv[m] = ivm[m * VD + v];
    }
    float w1r[50];
    if (lane < FC) {
        #pragma unroll
        for (int i = 0; i < 50; ++i) w1r[i] = w1[(wv * 50 + i) * FC + lane];
    } else {
        #pragma unroll
        for (int i = 0; i < 50; ++i) w1r[i] = 0.f;
    }
    const float w2f = (tid < FC) ? w2[tid] : 0.f;
    const float b2f = b2[0];

    const int* qrow_i  = qd  + b * SS;
    const int* qarow_i = qad + b * SS;
    const int jchunk = v / 50;
    const int wslot  = jchunk * 52 + (v - jchunk * 50);

    for (int t = 0; t < SS; ++t) {
        const int q  = __builtin_amdgcn_readfirstlane(qrow_i[t]);
        const int qa = __builtin_amdgcn_readfirstlane(qarow_i[t]);
        const float* wrow = Wtab + q * MEMN;

        u32 ea = 0;
        if (v < VD) ea = EA[(size_t)qa * VD + v];
        float ne = h16_to_f((u16)(ea & 0xffffu));   // -e
        float av = h16_to_f((u16)(ea >> 16));       //  a

        if (v < VD) {
            float rd0 = 0.f, rd1 = 0.f;
            #pragma unroll
            for (int m = 0; m < MEMN; m += 2) {
                float wm0 = wrow[m], wm1 = wrow[m + 1];
                rd0 = fmaf(wm0, mv[m], rd0);
                mv[m] = fmaf(wm0, fmaf(ne, mv[m], av), mv[m]);
                rd1 = fmaf(wm1, mv[m + 1], rd1);
                mv[m + 1] = fmaf(wm1, fmaf(ne, mv[m + 1], av), mv[m + 1]);
            }
            read_lds[wslot] = rd0 + rd1;
        }
        __syncthreads();

        float part = 0.f;
        {
            const float* rlc = read_lds + wv * 52;
            #pragma unroll
            for (int i = 0; i < 48; i += 4) {
                float4 x = *(const float4*)(rlc + i);
                part = fmaf(x.x, w1r[i],     part);
                part = fmaf(x.y, w1r[i + 1], part);
                part = fmaf(x.z, w1r[i + 2], part);
                part = fmaf(x.w, w1r[i + 3], part);
            }
            part = fmaf(rlc[48], w1r[48], part);
            part = fmaf(rlc[49], w1r[49], part);
        }
        if (lane < FC) part_lds[wv * 52 + lane] = part;
        __syncthreads();

        if (wv == 0) {
            float pf = 0.f;
            if (lane < FC) {
                float h = part_lds[lane] + part_lds[52 + lane] +
                          part_lds[104 + lane] + part_lds[156 + lane] +
                          Q1tab[q * FC + lane];
                pf = fast_tanh(h) * w2f;
            }
            #pragma unroll
            for (int off = 32; off >= 1; off >>= 1) pf += __shfl_xor(pf, off, 64);
            if (lane == 0) out[b * SS + t] = fast_sigmoid(pf + b2f);
        }
    }
}

extern "C" void kernel_launch(void* const* d_in, const int* in_sizes, int n_in,
                              void* d_out, int out_size, void* d_ws, size_t ws_size,
                              hipStream_t stream) {
    const int* qd  = (const int*)d_in[0];
    const int* qad = (const int*)d_in[1];
    const float* qemb  = (const float*)d_in[2];
    const float* qaemb = (const float*)d_in[3];
    const float* km    = (const float*)d_in[4];
    const float* ivm   = (const float*)d_in[5];
    const float* ew    = (const float*)d_in[6];
    const float* eb    = (const float*)d_in[7];
    const float* aw    = (const float*)d_in[8];
    const float* ab    = (const float*)d_in[9];
    const float* w1    = (const float*)d_in[10];
    const float* b1    = (const float*)d_in[11];
    const float* w2    = (const float*)d_in[12];
    const float* b2    = (const float*)d_in[13];
    float* out = (float*)d_out;
    (void)in_sizes; (void)n_in; (void)out_size;

    char* ws = (char*)d_ws;
    float* Wt  = (float*)(ws);                       // 1,000,200 -> pad 1,000,448
    float* Q1  = (float*)(ws + 1000448);             // 1,000,200 -> pad 1,000,448
    u32*   EA  = (u32*)  (ws + 2000896);             // 8,000,800 -> pad 8,001,024
    u16*   W1s = (u16*)  (ws + 10001920);            // 28,672    -> pad 32,768
    u32*   Wh  = (u32*)  (ws + 10034688);            // 640,128   -> pad 640,512
    u16*   RD  = (u16*)  (ws + 10675200);            // 163,840,000
    const size_t need = 10675200ull + 163840000ull + 512ull;

    // prep: EA + Wt/Wh/Q1 + W1s + zero outputs 1..3 (one dispatch)
    prep<<<PREP_G, 256, 0, stream>>>(qemb, km, w1, b1, qaemb, ew, eb, aw, ab,
                                     Wt, Wh, Q1, EA, W1s, out + (size_t)BB * SS);

    if (ws_size >= need) {
        dkvmn_state<<<BB / 2, 512, 0, stream>>>(qd, qad, Wh, EA, ivm, RD);
        mlp_pred<<<(BB * SS) / 64, 256, 0, stream>>>(RD, qd, Q1, W1s, w2, b2, out);
    } else {
        dkvmn_main<<<BB, 256, 0, stream>>>(qd, qad, Wt, Q1, EA, ivm, w1, w2, b2, out);
    }
}

// Round 9
// 435.684 us; speedup vs baseline: 1.2871x; 1.2871x over previous
//
#include <hip/hip_runtime.h>
#include <hip/hip_fp16.h>

// DKVMN forward, v26 = v25 with the register budget fixed.
//  R8 post-mortem: launch_bounds(512,8) forced VGPR<=64 and the allocator
//  capped at 32 -> massive scratch spills (FETCH 149->755MB, WRITE
//  180->868MB, ~5x TCC traffic; VALUBusy 52%). The residency lever ITSELF
//  worked: occupancy 34->72% as predicted. Decontaminate: launch_bounds
//  (512,4) -> allocator free up to 128 VGPR (v24's identical per-wave code
//  used 52; 52<=64 -> HW grants 8 waves/SIMD -> 4 blocks/CU -> full 32-wave
//  residency in ONE round, which R8 proved this geometry achieves).
//  Structure (== v25/v24): one block = one batch PAIR; waves 0-2 heavy
//  (batch 2p), 3-5 heavy (batch 2p+1), 6/7 tails. Per wave: private LDS
//  window (8 steps x 128B), 4 coalesced VMEM stage loads/group at s=0,
//  ds_writes at s=7, per-step w(t+1) prefetch into alternate reg buffer,
//  ea depth-2 per-lane VMEM, zero SMEM / zero barriers in the hot loop.
//  Math bit-identical to v18/v19/v24 (same fdot2+hfma2 order, same w bits).
//  k1 prep : EA {-e,a} f16 | Wt/Wh/Q1 | W1s pack | zero outputs 1..3.
//  k3 mlp_pred : MFMA 16x16x32 bf16 GEMM [B*S,224]@[224,64] + fused epilogue.
// Workspace: Wt 1MB | Q1 1MB | EA 8MB | W1s 32KB | Wh 0.64MB | RD 164MB.

#define NQ1   5001
#define NQA   10001
#define MEMN  50
#define KD    50
#define VD    200
#define FC    50
#define BB    2048
#define SS    200
#define EA_R  16
#define WHS   32       // Wh row stride in u32 (25 pairs + 7 zero pad, 128B)

#define EA_B   626     // ceil(10001/16)
#define WQ_B   1251    // ceil(5001/4)
#define PACK_B 8
#define PREP_G (EA_B + WQ_B + PACK_B)   // 1885 blocks

#define WG    8        // steps per window group; 25 groups * 8 = SS exactly

typedef unsigned int   u32;
typedef unsigned short u16;
typedef short    s8v __attribute__((ext_vector_type(8)));   // 8 bf16 (4 VGPRs)
typedef float    f4v __attribute__((ext_vector_type(4)));   // MFMA C/D
typedef _Float16 h2v __attribute__((ext_vector_type(2)));   // packed f16 pair
typedef u32      u4v __attribute__((ext_vector_type(4)));   // dwordx4

__device__ __forceinline__ float fast_sigmoid(float x) { return 1.f / (1.f + __expf(-x)); }
__device__ __forceinline__ float fast_tanh(float x) {
    float e2 = __expf(2.f * x);           // inf-safe
    return 1.f - 2.f / (e2 + 1.f);
}
__device__ __forceinline__ float bfu16_to_f(u16 u) {
    union { float f; u32 i; } x; x.i = ((u32)u) << 16; return x.f;
}
__device__ __forceinline__ u16 f_to_bfu16(float f) {   // RNE, finite inputs
    union { float f; u32 i; } x; x.f = f;
    return (u16)((x.i + 0x7fffu + ((x.i >> 16) & 1u)) >> 16);
}
__device__ __forceinline__ h2v u32_to_h2v(u32 u) {
    union { u32 i; h2v h; } x; x.i = u; return x.h;
}
__device__ __forceinline__ u16 f16bits(float f) {
    union { __half h; u16 u; } x; x.h = __float2half(f); return x.u;
}
__device__ __forceinline__ float h16_to_f(u16 u) {
    union { u16 u; __half h; } x; x.u = u; return __half2float(x.h);
}

// ---- merged prep: EA table | per-q tables | W1 pack | aux-output zeroing ----
__global__ __launch_bounds__(256) void prep(
        const float* __restrict__ qemb, const float* __restrict__ km,
        const float* __restrict__ w1,   const float* __restrict__ b1,
        const float* __restrict__ qaemb,
        const float* __restrict__ ew,   const float* __restrict__ ebias,
        const float* __restrict__ aw,   const float* __restrict__ abias,
        float* __restrict__ Wt, u32* __restrict__ Wh, float* __restrict__ Q1,
        u32* __restrict__ EA, u16* __restrict__ W1s,
        float* __restrict__ out_aux) {
    const int tid = threadIdx.x;
    const int blk = blockIdx.x;

    // every block zeroes its slice of outputs 1..3 (replaces hipMemsetAsync)
    for (size_t i = (size_t)blk * 256 + tid; i < 3ull * BB * SS;
         i += (size_t)PREP_G * 256)
        out_aux[i] = 0.f;

    __shared__ float smem[VD * EA_R];             // 12.8 KB (EA role); WQ uses 256

    if (blk < EA_B) {
        // ---------------- EA role: {-e, a} packed f16 ----------------
        const int r0 = blk * EA_R;
        if (tid < VD) {
            #pragma unroll
            for (int r = 0; r < EA_R; ++r) {
                int row = r0 + r;
                smem[tid * EA_R + r] = (row < NQA) ? qaemb[(size_t)row * VD + tid] : 0.f;
            }
        }
        __syncthreads();
        if (tid >= VD) return;

        float accE[EA_R], accA[EA_R];
        #pragma unroll
        for (int r = 0; r < EA_R; ++r) { accE[r] = 0.f; accA[r] = 0.f; }
        for (int k = 0; k < VD; ++k) {
            float we = ew[k * VD + tid];
            float wa = aw[k * VD + tid];
            #pragma unroll
            for (int r = 0; r < EA_R; ++r) {
                float qv = smem[k * EA_R + r];
                accE[r] = fmaf(qv, we, accE[r]);
                accA[r] = fmaf(qv, wa, accA[r]);
            }
        }
        float be = ebias[tid], ba = abias[tid];
        #pragma unroll
        for (int r = 0; r < EA_R; ++r) {
            int row = r0 + r;
            if (row < NQA) {
                u16 ne16 = f16bits(-fast_sigmoid(accE[r] + be));   // -e
                u16 a16  = f16bits(fast_tanh(accA[r] + ba));       //  a
                EA[(size_t)row * VD + tid] = (u32)ne16 | ((u32)a16 << 16);
            }
        }
    } else if (blk < EA_B + WQ_B) {
        // ---------------- WQ role (== proven build_wq, 4 q/block) ----------------
        const int lane = tid & 63;
        const int wv   = tid >> 6;
        const int q    = (blk - EA_B) * 4 + wv;
        const bool qok = q < NQ1;
        float* qrow = smem + wv * 64;             // 50 used per wave
        if (qok && lane < KD) qrow[lane] = qemb[q * KD + lane];
        __syncthreads();
        if (!qok) return;

        float s = -1e30f;
        if (lane < MEMN) {
            s = 0.f;
            #pragma unroll
            for (int k = 0; k < KD; ++k) s = fmaf(qrow[k], km[lane * KD + k], s);
        }
        float mx = s;
        #pragma unroll
        for (int off = 32; off >= 1; off >>= 1) mx = fmaxf(mx, __shfl_xor(mx, off, 64));
        float e = (lane < MEMN) ? __expf(s - mx) : 0.f;
        float sum = e;
        #pragma unroll
        for (int off = 32; off >= 1; off >>= 1) sum += __shfl_xor(sum, off, 64);
        float wv_ = (lane < MEMN) ? (e / sum) : 0.f;
        if (lane < MEMN) Wt[q * MEMN + lane] = wv_;

        // f16-pair row: lane i<25 packs (w[2i], w[2i+1]); pairs 25..31 zero
        float plo = __shfl(wv_, 2 * (lane & 31), 64);
        float phi = __shfl(wv_, 2 * (lane & 31) + 1, 64);
        if (lane < 25) {
            Wh[q * WHS + lane] = (u32)f16bits(plo) | ((u32)f16bits(phi) << 16);
        } else if (lane < WHS) {
            Wh[q * WHS + lane] = 0;
        }

        if (lane < FC) {
            float h = b1[lane];
            #pragma unroll
            for (int k = 0; k < KD; ++k)
                h = fmaf(qrow[k], w1[(VD + k) * FC + lane], h);
            Q1[q * FC + lane] = h;
        }
    } else {
        // ---------------- pack role (== proven pack_w1) ----------------
        for (int idx = (blk - EA_B - WQ_B) * 256 + tid; idx < 4 * 7 * 64 * 8;
             idx += PACK_B * 256) {
            int j    = idx & 7;
            int lane = (idx >> 3) & 63;
            int kt   = (idx >> 9) % 7;
            int nt   = idx / 3584;
            int k = kt * 32 + ((lane >> 4) << 3) + j;
            int n = nt * 16 + (lane & 15);
            float v = (k < VD && n < FC) ? w1[k * FC + n] : 0.f;
            W1s[idx] = f_to_bfu16(v);
        }
    }
}

// one recurrence step for 64 dense columns; w row in VGPRs (6x b128 + 1)
__device__ __forceinline__ void state_step_v(const u4v (&w)[6], u32 w6, u32 ea,
                                             h2v (&mv)[25], float& rdA, float& rdB) {
    // ea = {-e (lo f16), a (hi f16)}; broadcast halves via v_perm
    h2v nev2 = u32_to_h2v(__builtin_amdgcn_perm(ea, ea, 0x01000100u));
    h2v av2  = u32_to_h2v(__builtin_amdgcn_perm(ea, ea, 0x03020302u));
    rdA = 0.f; rdB = 0.f;
    #pragma unroll
    for (int i = 0; i < 25; i += 2) {        // 13 iters (i=24 single)
        u32 wu0 = (i < 24) ? w[i >> 2][i & 3] : w6;     // compile-time select
        h2v w0 = u32_to_h2v(wu0);
#if __has_builtin(__builtin_amdgcn_fdot2)
        rdA = __builtin_amdgcn_fdot2(w0, mv[i], rdA, false);
#else
        rdA = fmaf((float)w0.x, (float)mv[i].x,
              fmaf((float)w0.y, (float)mv[i].y, rdA));
#endif
        mv[i] = __builtin_elementwise_fma(
            w0, __builtin_elementwise_fma(nev2, mv[i], av2), mv[i]);
        if (i + 1 < 25) {
            h2v w1p = u32_to_h2v(w[(i + 1) >> 2][(i + 1) & 3]);
#if __has_builtin(__builtin_amdgcn_fdot2)
            rdB = __builtin_amdgcn_fdot2(w1p, mv[i + 1], rdB, false);
#else
            rdB = fmaf((float)w1p.x, (float)mv[i + 1].x,
                  fmaf((float)w1p.y, (float)mv[i + 1].y, rdB));
#endif
            mv[i + 1] = __builtin_elementwise_fma(
                w1p, __builtin_elementwise_fma(nev2, mv[i + 1], av2), mv[i + 1]);
        }
    }
}

// ---- recurrence: BB/2 blocks x 512 thr (8 waves) = one batch PAIR/block ----
//  waves 0-2: heavy roles 0-2, batch 2p; waves 3-5: heavy, batch 2p+1;
//  waves 6/7: tail, batch 2p / 2p+1. Per-wave structure == v24:
//  private win[wid][8][32]; per group 4 coalesced VMEM stage loads at s=0,
//  ds_writes at s=7; per step prefetch w(t+1) into alternate reg buffer at
//  step TOP; ea depth-2 per-lane VMEM; zero SMEM / zero barriers in loop.
//  launch_bounds(512,4): allocator free to 128 VGPR (uses ~52 -> HW grants
//  8 waves/SIMD -> 4 blocks/CU -> full residency), NO spills (R8 lesson).
__global__ __launch_bounds__(512, 4) void dkvmn_state(
        const int* __restrict__ qd, const int* __restrict__ qad,
        const u32* __restrict__ Wh, const u32* __restrict__ EA,
        const float* __restrict__ ivm, u16* __restrict__ READ) {
    const int tid  = threadIdx.x;          // 0..511
    const int lane = tid & 63;
    const int wid  = tid >> 6;             // 0..7
    const int blk  = blockIdx.x;           // 0..BB/2-1

    __shared__ int qsf[2 * SS], qasf[2 * SS];   // 3.2 KB (both batches)
    __shared__ u32 win[6][WG][WHS];             // 6 KB: per-heavy-wave window

    for (int i = tid; i < 2 * SS; i += 512) {
        qsf[i]  = qd[(size_t)blk * 2 * SS + i];
        qasf[i] = qad[(size_t)blk * 2 * SS + i];
    }
    __syncthreads();                        // the ONLY barrier

    if (wid < 6) {
        // ---------------- heavy wave: 64 unique columns ----------------
        const int bat  = (wid >= 3);        // batch within pair
        const int role = wid - bat * 3;     // 0..2
        const int base = (blk * 2 + bat) * SS;
        const int* qp  = qsf  + bat * SS;
        const int* qap = qasf + bat * SS;

        const int v    = role * 64 + lane;  // < 192, every lane unique
        const int word = lane & 31;         // word within Wh row
        const int half = lane >> 5;         // 0,1: row-within-pair

        h2v mv[25];                         // pair i = slots (2i, 2i+1)
        #pragma unroll
        for (int i = 0; i < 25; ++i) {
            mv[i].x = (_Float16)ivm[(2 * i) * VD + v];
            mv[i].y = (_Float16)ivm[(2 * i + 1) * VD + v];
        }

        // ---- prologue: stage group 0, prefetch w(0), init qa/ea pipes ----
        u32 wst[4];
        {
            int qg0[4];
            #pragma unroll
            for (int i = 0; i < 4; ++i) qg0[i] = qp[i * 2 + half];
            #pragma unroll
            for (int i = 0; i < 4; ++i)
                wst[i] = Wh[(size_t)qg0[i] * WHS + word];
            #pragma unroll
            for (int i = 0; i < 4; ++i)
                win[wid][i * 2 + half][word] = wst[i];   // auto vmcnt wait
        }
        int qstage[4];                      // rows for group-1 staging
        #pragma unroll
        for (int i = 0; i < 4; ++i) qstage[i] = qp[WG + i * 2 + half];

        u4v wrb[2][6]; u32 wrb6[2];         // w reg double buffer
        {
            const u32* wp = &win[wid][0][0];
            #pragma unroll
            for (int j = 0; j < 6; ++j) wrb[0][j] = *(const u4v*)(wp + j * 4);
            wrb6[0] = wp[24];
        }

        int qa2 = qap[2], qa3 = qap[3];
        u32 ea_c = EA[(size_t)qap[0] * VD + v];
        u32 ea_n = EA[(size_t)qap[1] * VD + v];

        // ---- main loop: 25 groups x 8 steps, barrier-free ----
        for (int g = 0; g < SS / WG; ++g) {
            #pragma unroll
            for (int s = 0; s < WG; ++s) {
                const int t   = g * WG + s;
                const int cur = s & 1;
                const int nxt = cur ^ 1;

                if (s == 0) {
                    // issue coalesced VMEM stage loads for group g+1
                    #pragma unroll
                    for (int i = 0; i < 4; ++i)
                        wst[i] = Wh[(size_t)qstage[i] * WHS + word];
                }
                if (s == WG - 1) {
                    // write group g+1 into window (7-step vmcnt cover),
                    // BEFORE this step's w prefetch reads slot 0
                    #pragma unroll
                    for (int i = 0; i < 4; ++i)
                        win[wid][i * 2 + half][word] = wst[i];
                    // rows for group g+2 staging (consumed next s==0)
                    #pragma unroll
                    for (int i = 0; i < 4; ++i) {
                        int idx = (g + 2) * WG + i * 2 + half;
                        idx = (idx < SS) ? idx : (SS - 1);
                        qstage[i] = qp[idx];
                    }
                }

                // prefetch w(t+1) into alternate buffer (full-step cover)
                {
                    const u32* wp = &win[wid][(s + 1) & (WG - 1)][0];
                    #pragma unroll
                    for (int j = 0; j < 6; ++j)
                        wrb[nxt][j] = *(const u4v*)(wp + j * 4);
                    wrb6[nxt] = wp[24];
                }

                // ea for t+2 (depth-2, per-lane coalesced)
                u32 ea_f = EA[(size_t)qa2 * VD + v];
                // qa for t+4 (reg pipeline via in-order DS)
                int t4 = t + 4; t4 = (t4 < SS) ? t4 : (SS - 1);
                int qa_nn = qap[t4];

                // consume w(t), ea(t)
                float rdA, rdB;
                state_step_v(wrb[cur], wrb6[cur], ea_c, mv, rdA, rdB);
                READ[(size_t)(base + t) * VD + v] = f_to_bfu16(rdA + rdB);

                qa2 = qa3; qa3 = qa_nn;
                ea_c = ea_n; ea_n = ea_f;
            }
        }
    } else {
        // ---------------- tail wave: v = 192..199, 8 slot-groups ----------------
        const int bat  = wid - 6;
        const int base = (blk * 2 + bat) * SS;
        const int* qp  = qsf  + bat * SS;
        const int* qap = qasf + bat * SS;

        const int v8  = lane & 7;
        const int grp = lane >> 3;         // owns pairs grp*4 .. grp*4+3
        const int v   = 192 + v8;

        h2v mv4[4];
        #pragma unroll
        for (int j = 0; j < 4; ++j) {
            int p = grp * 4 + j;
            if (p < 25) {
                mv4[j].x = (_Float16)ivm[(2 * p) * VD + v];
                mv4[j].y = (_Float16)ivm[(2 * p + 1) * VD + v];
            } else {                       // padded pairs: w=0 keeps them 0
                mv4[j].x = (_Float16)0.f;
                mv4[j].y = (_Float16)0.f;
            }
        }

        int q0 = qp[0], q1 = qp[1];
        u32 ea_c = EA[(size_t)qap[0] * VD + v];
        u32 ea_n = EA[(size_t)qap[1] * VD + v];
        u4v wq_c = *(const u4v*)(Wh + (size_t)q0 * WHS + grp * 4);
        u4v wq_n = *(const u4v*)(Wh + (size_t)q1 * WHS + grp * 4);

        for (int t = 0; t < SS; ++t) {
            int tn = t + 2; tn = (tn < SS) ? tn : (SS - 1);
            int q_nn  = qp[tn];
            int qa_nn = qap[tn];
            u32 ea_nn = EA[(size_t)qa_nn * VD + v];
            u4v wq_nn = *(const u4v*)(Wh + (size_t)q_nn * WHS + grp * 4);

            h2v nev2 = u32_to_h2v(__builtin_amdgcn_perm(ea_c, ea_c, 0x01000100u));
            h2v av2  = u32_to_h2v(__builtin_amdgcn_perm(ea_c, ea_c, 0x03020302u));

            float rd = 0.f;
            #pragma unroll
            for (int j = 0; j < 4; ++j) {
                h2v w2 = u32_to_h2v(wq_c[j]);
#if __has_builtin(__builtin_amdgcn_fdot2)
                rd = __builtin_amdgcn_fdot2(w2, mv4[j], rd, false);
#else
                rd = fmaf((float)w2.x, (float)mv4[j].x,
                     fmaf((float)w2.y, (float)mv4[j].y, rd));
#endif
                mv4[j] = __builtin_elementwise_fma(
                    w2, __builtin_elementwise_fma(nev2, mv4[j], av2), mv4[j]);
            }
            // reduce over the 8 slot-groups (lane stride 8)
            rd += __shfl_xor(rd, 8, 64);
            rd += __shfl_xor(rd, 16, 64);
            rd += __shfl_xor(rd, 32, 64);
            if (grp == 0)
                READ[(size_t)(base + t) * VD + v] = f_to_bfu16(rd);

            ea_c = ea_n; ea_n = ea_nn;
            wq_c = wq_n; wq_n = wq_nn;
        }
    }
}

// ---- prediction MLP via MFMA: per wave one 16-row strip, K=224, N=64 ----
__global__ __launch_bounds__(256) void mlp_pred(
        const u16* __restrict__ RD, const int* __restrict__ qd,
        const float* __restrict__ Q1tab, const u16* __restrict__ W1s,
        const float* __restrict__ w2, const float* __restrict__ b2,
        float* __restrict__ out) {
    const int tid  = threadIdx.x;
    const int lane = tid & 63;
    const int wv   = tid >> 6;
    const int strip = blockIdx.x * 4 + wv;
    const int row0  = strip * 16;

    const int mrow = lane & 15;        // A row within strip / C-D col (feature)
    const int quad = lane >> 4;

    s8v a[7];
    {
        const u16* arow = RD + (size_t)(row0 + mrow) * VD + quad * 8;
        #pragma unroll
        for (int kt = 0; kt < 7; ++kt)
            a[kt] = *(const s8v*)(arow + kt * 32);   // k>=200 garbage * B=0
    }

    const float b2f = b2[0];
    float pf[4] = {0.f, 0.f, 0.f, 0.f};

    #pragma unroll
    for (int nt = 0; nt < 4; ++nt) {
        s8v bfr[7];
        #pragma unroll
        for (int kt = 0; kt < 7; ++kt)
            bfr[kt] = *(const s8v*)(W1s + (((nt * 7 + kt) * 64) + lane) * 8);

        f4v acc = {0.f, 0.f, 0.f, 0.f};
        #pragma unroll
        for (int kt = 0; kt < 7; ++kt)
            acc = __builtin_amdgcn_mfma_f32_16x16x32_bf16(a[kt], bfr[kt], acc, 0, 0, 0);

        const int f = nt * 16 + mrow;                  // output feature col
        const float w2f = (f < FC) ? w2[f] : 0.f;
        #pragma unroll
        for (int r = 0; r < 4; ++r) {
            int row = row0 + quad * 4 + r;
            float h = acc[r] + Q1tab[qd[row] * FC + f];
            pf[r] = fmaf(fast_tanh(h), w2f, pf[r]);
        }
    }

    #pragma unroll
    for (int r = 0; r < 4; ++r) {
        float s = pf[r];
        s += __shfl_xor(s, 1, 64);
        s += __shfl_xor(s, 2, 64);
        s += __shfl_xor(s, 4, 64);
        s += __shfl_xor(s, 8, 64);
        if (mrow == 0)
            out[row0 + quad * 4 + r] = fast_sigmoid(s + b2f);
    }
}

// ---- fallback (barrier version, f32) if workspace too small ----
__global__ void dkvmn_main(const int* __restrict__ qd, const int* __restrict__ qad,
                           const float* __restrict__ Wtab, const float* __restrict__ Q1tab,
                           const u32* __restrict__ EA,
                           const float* __restrict__ ivm,
                           const float* __restrict__ w1,
                           const float* __restrict__ w2,
                           const float* __restrict__ b2,
                           float* __restrict__ out) {
    const int tid  = threadIdx.x;
    const int b    = blockIdx.x;
    const int v    = tid;
    const int lane = tid & 63;
    const int wv   = tid >> 6;

    __shared__ alignas(16) float read_lds[4 * 52];
    __shared__ alignas(16) float part_lds[4 * 52];

    float mv[MEMN];
    if (v < VD) {
        #pragma unroll
        for (int m = 0; m < MEMN; ++m) mv[m] = ivm[m * VD + v];
    }
    float w1r[50];
    if (lane < FC) {
        #pragma unroll
        for (int i = 0; i < 50; ++i) w1r[i] = w1[(wv * 50 + i) * FC + lane];
    } else {
        #pragma unroll
        for (int i = 0; i < 50; ++i) w1r[i] = 0.f;
    }
    const float w2f = (tid < FC) ? w2[tid] : 0.f;
    const float b2f = b2[0];

    const int* qrow_i  = qd  + b * SS;
    const int* qarow_i = qad + b * SS;
    const int jchunk = v / 50;
    const int wslot  = jchunk * 52 + (v - jchunk * 50);

    for (int t = 0; t < SS; ++t) {
        const int q  = __builtin_amdgcn_readfirstlane(qrow_i[t]);
        const int qa = __builtin_amdgcn_readfirstlane(qarow_i[t]);
        const float* wrow = Wtab + q * MEMN;

        u32 ea = 0;
        if (v < VD) ea = EA[(size_t)qa * VD + v];
        float ne = h16_to_f((u16)(ea & 0xffffu));   // -e
        float av = h16_to_f((u16)(ea >> 16));       //  a

        if (v < VD) {
            float rd0 = 0.f, rd1 = 0.f;
            #pragma unroll
            for (int m = 0; m < MEMN; m += 2) {
                float wm0 = wrow[m], wm1 = wrow[m + 1];
                rd0 = fmaf(wm0, mv[m], rd0);
                mv[m] = fmaf(wm0, fmaf(ne, mv[m], av), mv[m]);
                rd1 = fmaf(wm1, mv[m + 1], rd1);
                mv[m + 1] = fmaf(wm1, fmaf(ne, mv[m + 1], av), mv[m + 1]);
            }
            read_lds[wslot] = rd0 + rd1;
        }
        __syncthreads();

        float part = 0.f;
        {
            const float* rlc = read_lds + wv * 52;
            #pragma unroll
            for (int i = 0; i < 48; i += 4) {
                float4 x = *(const float4*)(rlc + i);
                part = fmaf(x.x, w1r[i],     part);
                part = fmaf(x.y, w1r[i + 1], part);
                part = fmaf(x.z, w1r[i + 2], part);
                part = fmaf(x.w, w1r[i + 3], part);
            }
            part = fmaf(rlc[48], w1r[48], part);
            part = fmaf(rlc[49], w1r[49], part);
        }
        if (lane < FC) part_lds[wv * 52 + lane] = part;
        __syncthreads();

        if (wv == 0) {
            float pf = 0.f;
            if (lane < FC) {
                float h = part_lds[lane] + part_lds[52 + lane] +
                          part_lds[104 + lane] + part_lds[156 + lane] +
                          Q1tab[q * FC + lane];
                pf = fast_tanh(h) * w2f;
            }
            #pragma unroll
            for (int off = 32; off >= 1; off >>= 1) pf += __shfl_xor(pf, off, 64);
            if (lane == 0) out[b * SS + t] = fast_sigmoid(pf + b2f);
        }
    }
}

extern "C" void kernel_launch(void* const* d_in, const int* in_sizes, int n_in,
                              void* d_out, int out_size, void* d_ws, size_t ws_size,
                              hipStream_t stream) {
    const int* qd  = (const int*)d_in[0];
    const int* qad = (const int*)d_in[1];
    const float* qemb  = (const float*)d_in[2];
    const float* qaemb = (const float*)d_in[3];
    const float* km    = (const float*)d_in[4];
    const float* ivm   = (const float*)d_in[5];
    const float* ew    = (const float*)d_in[6];
    const float* eb    = (const float*)d_in[7];
    const float* aw    = (const float*)d_in[8];
    const float* ab    = (const float*)d_in[9];
    const float* w1    = (const float*)d_in[10];
    const float* b1    = (const float*)d_in[11];
    const float* w2    = (const float*)d_in[12];
    const float* b2    = (const float*)d_in[13];
    float* out = (float*)d_out;
    (void)in_sizes; (void)n_in; (void)out_size;

    char* ws = (char*)d_ws;
    float* Wt  = (float*)(ws);                       // 1,000,200 -> pad 1,000,448
    float* Q1  = (float*)(ws + 1000448);             // 1,000,200 -> pad 1,000,448
    u32*   EA  = (u32*)  (ws + 2000896);             // 8,000,800 -> pad 8,001,024
    u16*   W1s = (u16*)  (ws + 10001920);            // 28,672    -> pad 32,768
    u32*   Wh  = (u32*)  (ws + 10034688);            // 640,128   -> pad 640,512
    u16*   RD  = (u16*)  (ws + 10675200);            // 163,840,000
    const size_t need = 10675200ull + 163840000ull + 512ull;

    // prep: EA + Wt/Wh/Q1 + W1s + zero outputs 1..3 (one dispatch)
    prep<<<PREP_G, 256, 0, stream>>>(qemb, km, w1, b1, qaemb, ew, eb, aw, ab,
                                     Wt, Wh, Q1, EA, W1s, out + (size_t)BB * SS);

    if (ws_size >= need) {
        dkvmn_state<<<BB / 2, 512, 0, stream>>>(qd, qad, Wh, EA, ivm, RD);
        mlp_pred<<<(BB * SS) / 64, 256, 0, stream>>>(RD, qd, Q1, W1s, w2, b2, out);
    } else {
        dkvmn_main<<<BB, 256, 0, stream>>>(qd, qad, Wt, Q1, EA, ivm, w1, w2, b2, out);
    }
}

// Round 10
// 432.530 us; speedup vs baseline: 1.2965x; 1.0073x over previous
//
#include <hip/hip_runtime.h>
#include <hip/hip_fp16.h>

// DKVMN forward, v27 = v26 with SIMD-balanced 16-wave blocks.
//  R9: no spills (VGPR 56), state 306us, VALUBusy 72.5%. Ledger: issue work
//  invariant (~220us), stall ~85us invariant to delivery AND occupancy.
//  New model: waves map to SIMDs by wid&3. v26's 8-wave block (tails at wid
//  6,7) loads SIMD0/1 with 8 heavy waves (~3040cyc/step-round) vs SIMD2/3
//  4 heavy+4 tail (~2120) -> wall set by heavy-only SIMDs; avg == measured
//  72%. Every prior geometry had this flaw (v24's 2-wave blocks used SIMD0/1
//  only). v27: 1024-thr block = 4 batches, 12 heavy (wid 0..11, bat=wid/3,
//  role=wid%3) + 4 tail (wid 12..15) -> wid%4 gives EVERY SIMD 3 heavy + 1
//  tail, balanced by construction. Grid 512 = exactly 2 blocks/CU, one fill
//  round. launch_bounds(1024,4): VGPR cap 128, natural 56 -> 8 waves/SIMD.
//  Issue trims: qas staged premultiplied by VD (kills per-step ea addr mul);
//  strength-reduced READ offsets. Per-wave code else identical to v26.
//  Math bit-identical to v18..v26 (same fdot2+hfma2 order, same w bits).
//  k1 prep : EA {-e,a} f16 | Wt/Wh/Q1 | W1s pack | zero outputs 1..3.
//  k3 mlp_pred : MFMA 16x16x32 bf16 GEMM [B*S,224]@[224,64] + fused epilogue.
// Workspace: Wt 1MB | Q1 1MB | EA 8MB | W1s 32KB | Wh 0.64MB | RD 164MB.

#define NQ1   5001
#define NQA   10001
#define MEMN  50
#define KD    50
#define VD    200
#define FC    50
#define BB    2048
#define SS    200
#define EA_R  16
#define WHS   32       // Wh row stride in u32 (25 pairs + 7 zero pad, 128B)

#define EA_B   626     // ceil(10001/16)
#define WQ_B   1251    // ceil(5001/4)
#define PACK_B 8
#define PREP_G (EA_B + WQ_B + PACK_B)   // 1885 blocks

#define WG    8        // steps per window group; 25 groups * 8 = SS exactly

typedef unsigned int   u32;
typedef unsigned short u16;
typedef short    s8v __attribute__((ext_vector_type(8)));   // 8 bf16 (4 VGPRs)
typedef float    f4v __attribute__((ext_vector_type(4)));   // MFMA C/D
typedef _Float16 h2v __attribute__((ext_vector_type(2)));   // packed f16 pair
typedef u32      u4v __attribute__((ext_vector_type(4)));   // dwordx4

__device__ __forceinline__ float fast_sigmoid(float x) { return 1.f / (1.f + __expf(-x)); }
__device__ __forceinline__ float fast_tanh(float x) {
    float e2 = __expf(2.f * x);           // inf-safe
    return 1.f - 2.f / (e2 + 1.f);
}
__device__ __forceinline__ float bfu16_to_f(u16 u) {
    union { float f; u32 i; } x; x.i = ((u32)u) << 16; return x.f;
}
__device__ __forceinline__ u16 f_to_bfu16(float f) {   // RNE, finite inputs
    union { float f; u32 i; } x; x.f = f;
    return (u16)((x.i + 0x7fffu + ((x.i >> 16) & 1u)) >> 16);
}
__device__ __forceinline__ h2v u32_to_h2v(u32 u) {
    union { u32 i; h2v h; } x; x.i = u; return x.h;
}
__device__ __forceinline__ u16 f16bits(float f) {
    union { __half h; u16 u; } x; x.h = __float2half(f); return x.u;
}
__device__ __forceinline__ float h16_to_f(u16 u) {
    union { u16 u; __half h; } x; x.u = u; return __half2float(x.h);
}

// ---- merged prep: EA table | per-q tables | W1 pack | aux-output zeroing ----
__global__ __launch_bounds__(256) void prep(
        const float* __restrict__ qemb, const float* __restrict__ km,
        const float* __restrict__ w1,   const float* __restrict__ b1,
        const float* __restrict__ qaemb,
        const float* __restrict__ ew,   const float* __restrict__ ebias,
        const float* __restrict__ aw,   const float* __restrict__ abias,
        float* __restrict__ Wt, u32* __restrict__ Wh, float* __restrict__ Q1,
        u32* __restrict__ EA, u16* __restrict__ W1s,
        float* __restrict__ out_aux) {
    const int tid = threadIdx.x;
    const int blk = blockIdx.x;

    // every block zeroes its slice of outputs 1..3 (replaces hipMemsetAsync)
    for (size_t i = (size_t)blk * 256 + tid; i < 3ull * BB * SS;
         i += (size_t)PREP_G * 256)
        out_aux[i] = 0.f;

    __shared__ float smem[VD * EA_R];             // 12.8 KB (EA role); WQ uses 256

    if (blk < EA_B) {
        // ---------------- EA role: {-e, a} packed f16 ----------------
        const int r0 = blk * EA_R;
        if (tid < VD) {
            #pragma unroll
            for (int r = 0; r < EA_R; ++r) {
                int row = r0 + r;
                smem[tid * EA_R + r] = (row < NQA) ? qaemb[(size_t)row * VD + tid] : 0.f;
            }
        }
        __syncthreads();
        if (tid >= VD) return;

        float accE[EA_R], accA[EA_R];
        #pragma unroll
        for (int r = 0; r < EA_R; ++r) { accE[r] = 0.f; accA[r] = 0.f; }
        for (int k = 0; k < VD; ++k) {
            float we = ew[k * VD + tid];
            float wa = aw[k * VD + tid];
            #pragma unroll
            for (int r = 0; r < EA_R; ++r) {
                float qv = smem[k * EA_R + r];
                accE[r] = fmaf(qv, we, accE[r]);
                accA[r] = fmaf(qv, wa, accA[r]);
            }
        }
        float be = ebias[tid], ba = abias[tid];
        #pragma unroll
        for (int r = 0; r < EA_R; ++r) {
            int row = r0 + r;
            if (row < NQA) {
                u16 ne16 = f16bits(-fast_sigmoid(accE[r] + be));   // -e
                u16 a16  = f16bits(fast_tanh(accA[r] + ba));       //  a
                EA[(size_t)row * VD + tid] = (u32)ne16 | ((u32)a16 << 16);
            }
        }
    } else if (blk < EA_B + WQ_B) {
        // ---------------- WQ role (== proven build_wq, 4 q/block) ----------------
        const int lane = tid & 63;
        const int wv   = tid >> 6;
        const int q    = (blk - EA_B) * 4 + wv;
        const bool qok = q < NQ1;
        float* qrow = smem + wv * 64;             // 50 used per wave
        if (qok && lane < KD) qrow[lane] = qemb[q * KD + lane];
        __syncthreads();
        if (!qok) return;

        float s = -1e30f;
        if (lane < MEMN) {
            s = 0.f;
            #pragma unroll
            for (int k = 0; k < KD; ++k) s = fmaf(qrow[k], km[lane * KD + k], s);
        }
        float mx = s;
        #pragma unroll
        for (int off = 32; off >= 1; off >>= 1) mx = fmaxf(mx, __shfl_xor(mx, off, 64));
        float e = (lane < MEMN) ? __expf(s - mx) : 0.f;
        float sum = e;
        #pragma unroll
        for (int off = 32; off >= 1; off >>= 1) sum += __shfl_xor(sum, off, 64);
        float wv_ = (lane < MEMN) ? (e / sum) : 0.f;
        if (lane < MEMN) Wt[q * MEMN + lane] = wv_;

        // f16-pair row: lane i<25 packs (w[2i], w[2i+1]); pairs 25..31 zero
        float plo = __shfl(wv_, 2 * (lane & 31), 64);
        float phi = __shfl(wv_, 2 * (lane & 31) + 1, 64);
        if (lane < 25) {
            Wh[q * WHS + lane] = (u32)f16bits(plo) | ((u32)f16bits(phi) << 16);
        } else if (lane < WHS) {
            Wh[q * WHS + lane] = 0;
        }

        if (lane < FC) {
            float h = b1[lane];
            #pragma unroll
            for (int k = 0; k < KD; ++k)
                h = fmaf(qrow[k], w1[(VD + k) * FC + lane], h);
            Q1[q * FC + lane] = h;
        }
    } else {
        // ---------------- pack role (== proven pack_w1) ----------------
        for (int idx = (blk - EA_B - WQ_B) * 256 + tid; idx < 4 * 7 * 64 * 8;
             idx += PACK_B * 256) {
            int j    = idx & 7;
            int lane = (idx >> 3) & 63;
            int kt   = (idx >> 9) % 7;
            int nt   = idx / 3584;
            int k = kt * 32 + ((lane >> 4) << 3) + j;
            int n = nt * 16 + (lane & 15);
            float v = (k < VD && n < FC) ? w1[k * FC + n] : 0.f;
            W1s[idx] = f_to_bfu16(v);
        }
    }
}

// one recurrence step for 64 dense columns; w row in VGPRs (6x b128 + 1)
__device__ __forceinline__ void state_step_v(const u4v (&w)[6], u32 w6, u32 ea,
                                             h2v (&mv)[25], float& rdA, float& rdB) {
    // ea = {-e (lo f16), a (hi f16)}; broadcast halves via v_perm
    h2v nev2 = u32_to_h2v(__builtin_amdgcn_perm(ea, ea, 0x01000100u));
    h2v av2  = u32_to_h2v(__builtin_amdgcn_perm(ea, ea, 0x03020302u));
    rdA = 0.f; rdB = 0.f;
    #pragma unroll
    for (int i = 0; i < 25; i += 2) {        // 13 iters (i=24 single)
        u32 wu0 = (i < 24) ? w[i >> 2][i & 3] : w6;     // compile-time select
        h2v w0 = u32_to_h2v(wu0);
#if __has_builtin(__builtin_amdgcn_fdot2)
        rdA = __builtin_amdgcn_fdot2(w0, mv[i], rdA, false);
#else
        rdA = fmaf((float)w0.x, (float)mv[i].x,
              fmaf((float)w0.y, (float)mv[i].y, rdA));
#endif
        mv[i] = __builtin_elementwise_fma(
            w0, __builtin_elementwise_fma(nev2, mv[i], av2), mv[i]);
        if (i + 1 < 25) {
            h2v w1p = u32_to_h2v(w[(i + 1) >> 2][(i + 1) & 3]);
#if __has_builtin(__builtin_amdgcn_fdot2)
            rdB = __builtin_amdgcn_fdot2(w1p, mv[i + 1], rdB, false);
#else
            rdB = fmaf((float)w1p.x, (float)mv[i + 1].x,
                  fmaf((float)w1p.y, (float)mv[i + 1].y, rdB));
#endif
            mv[i + 1] = __builtin_elementwise_fma(
                w1p, __builtin_elementwise_fma(nev2, mv[i + 1], av2), mv[i + 1]);
        }
    }
}

// ---- recurrence: BB/4 blocks x 1024 thr (16 waves) = 4 batches/block ----
//  wid 0..11 heavy (bat = wid/3, role = wid%3); wid 12..15 tail (bat=wid-12).
//  wid%4 -> SIMD: every SIMD gets exactly 3 heavy + 1 tail (balanced).
//  Per-wave structure == v24/v26: private win[wid][8][32]; per group 4
//  coalesced VMEM stage loads at s=0, ds_writes at s=7; per step prefetch
//  w(t+1) into alternate reg buffer at step TOP; ea depth-2 per-lane VMEM
//  (qas staged PREMULTIPLIED by VD); zero SMEM / zero barriers in loop.
__global__ __launch_bounds__(1024, 4) void dkvmn_state(
        const int* __restrict__ qd, const int* __restrict__ qad,
        const u32* __restrict__ Wh, const u32* __restrict__ EA,
        const float* __restrict__ ivm, u16* __restrict__ READ) {
    const int tid  = threadIdx.x;          // 0..1023
    const int lane = tid & 63;
    const int wid  = tid >> 6;             // 0..15
    const int blk  = blockIdx.x;           // 0..BB/4-1

    __shared__ int qsf[4 * SS], qasf[4 * SS];   // 6.4 KB (4 batches; qasf premult VD)
    __shared__ u32 win[12][WG][WHS];            // 12 KB: per-heavy-wave window

    for (int i = tid; i < 4 * SS; i += 1024) {
        qsf[i]  = qd[(size_t)blk * 4 * SS + i];
        qasf[i] = qad[(size_t)blk * 4 * SS + i] * VD;
    }
    __syncthreads();                        // the ONLY barrier

    if (wid < 12) {
        // ---------------- heavy wave: 64 unique columns ----------------
        const int bat  = wid / 3;           // batch within quad (0..3)
        const int role = wid - bat * 3;     // 0..2
        const int base = (blk * 4 + bat) * SS;
        const int* qp  = qsf  + bat * SS;
        const int* qap = qasf + bat * SS;   // premultiplied by VD

        const int v    = role * 64 + lane;  // < 192, every lane unique
        const int word = lane & 31;         // word within Wh row
        const int half = lane >> 5;         // 0,1: row-within-pair

        h2v mv[25];                         // pair i = slots (2i, 2i+1)
        #pragma unroll
        for (int i = 0; i < 25; ++i) {
            mv[i].x = (_Float16)ivm[(2 * i) * VD + v];
            mv[i].y = (_Float16)ivm[(2 * i + 1) * VD + v];
        }

        // ---- prologue: stage group 0, prefetch w(0), init qa/ea pipes ----
        u32 wst[4];
        {
            int qg0[4];
            #pragma unroll
            for (int i = 0; i < 4; ++i) qg0[i] = qp[i * 2 + half];
            #pragma unroll
            for (int i = 0; i < 4; ++i)
                wst[i] = Wh[(size_t)qg0[i] * WHS + word];
            #pragma unroll
            for (int i = 0; i < 4; ++i)
                win[wid][i * 2 + half][word] = wst[i];   // auto vmcnt wait
        }
        int qstage[4];                      // rows for group-1 staging
        #pragma unroll
        for (int i = 0; i < 4; ++i) qstage[i] = qp[WG + i * 2 + half];

        u4v wrb[2][6]; u32 wrb6[2];         // w reg double buffer
        {
            const u32* wp = &win[wid][0][0];
            #pragma unroll
            for (int j = 0; j < 6; ++j) wrb[0][j] = *(const u4v*)(wp + j * 4);
            wrb6[0] = wp[24];
        }

        int qa2 = qap[2], qa3 = qap[3];     // premultiplied
        u32 ea_c = EA[(size_t)qap[0] + v];
        u32 ea_n = EA[(size_t)qap[1] + v];

        size_t ro = (size_t)base * VD + v;  // strength-reduced READ offset

        // ---- main loop: 25 groups x 8 steps, barrier-free ----
        for (int g = 0; g < SS / WG; ++g) {
            #pragma unroll
            for (int s = 0; s < WG; ++s) {
                const int t   = g * WG + s;
                const int cur = s & 1;
                const int nxt = cur ^ 1;

                if (s == 0) {
                    // issue coalesced VMEM stage loads for group g+1
                    #pragma unroll
                    for (int i = 0; i < 4; ++i)
                        wst[i] = Wh[(size_t)qstage[i] * WHS + word];
                }
                if (s == WG - 1) {
                    // write group g+1 into window (7-step vmcnt cover),
                    // BEFORE this step's w prefetch reads slot 0
                    #pragma unroll
                    for (int i = 0; i < 4; ++i)
                        win[wid][i * 2 + half][word] = wst[i];
                    // rows for group g+2 staging (consumed next s==0)
                    #pragma unroll
                    for (int i = 0; i < 4; ++i) {
                        int idx = (g + 2) * WG + i * 2 + half;
                        idx = (idx < SS) ? idx : (SS - 1);
                        qstage[i] = qp[idx];
                    }
                }

                // prefetch w(t+1) into alternate buffer (full-step cover)
                {
                    const u32* wp = &win[wid][(s + 1) & (WG - 1)][0];
                    #pragma unroll
                    for (int j = 0; j < 6; ++j)
                        wrb[nxt][j] = *(const u4v*)(wp + j * 4);
                    wrb6[nxt] = wp[24];
                }

                // ea for t+2 (depth-2, per-lane coalesced, premult addr)
                u32 ea_f = EA[(size_t)qa2 + v];
                // qa for t+4 (reg pipeline via in-order DS)
                int t4 = t + 4; t4 = (t4 < SS) ? t4 : (SS - 1);
                int qa_nn = qap[t4];

                // consume w(t), ea(t)
                float rdA, rdB;
                state_step_v(wrb[cur], wrb6[cur], ea_c, mv, rdA, rdB);
                READ[ro] = f_to_bfu16(rdA + rdB);
                ro += VD;

                qa2 = qa3; qa3 = qa_nn;
                ea_c = ea_n; ea_n = ea_f;
            }
        }
    } else {
        // ---------------- tail wave: v = 192..199, 8 slot-groups ----------------
        const int bat  = wid - 12;
        const int base = (blk * 4 + bat) * SS;
        const int* qp  = qsf  + bat * SS;
        const int* qap = qasf + bat * SS;   // premultiplied by VD

        const int v8  = lane & 7;
        const int grp = lane >> 3;         // owns pairs grp*4 .. grp*4+3
        const int v   = 192 + v8;

        h2v mv4[4];
        #pragma unroll
        for (int j = 0; j < 4; ++j) {
            int p = grp * 4 + j;
            if (p < 25) {
                mv4[j].x = (_Float16)ivm[(2 * p) * VD + v];
                mv4[j].y = (_Float16)ivm[(2 * p + 1) * VD + v];
            } else {                       // padded pairs: w=0 keeps them 0
                mv4[j].x = (_Float16)0.f;
                mv4[j].y = (_Float16)0.f;
            }
        }

        int q0 = qp[0], q1 = qp[1];
        u32 ea_c = EA[(size_t)qap[0] + v];
        u32 ea_n = EA[(size_t)qap[1] + v];
        u4v wq_c = *(const u4v*)(Wh + (size_t)q0 * WHS + grp * 4);
        u4v wq_n = *(const u4v*)(Wh + (size_t)q1 * WHS + grp * 4);

        size_t ro = (size_t)base * VD + v;

        for (int t = 0; t < SS; ++t) {
            int tn = t + 2; tn = (tn < SS) ? tn : (SS - 1);
            int q_nn  = qp[tn];
            int qa_nn = qap[tn];
            u32 ea_nn = EA[(size_t)qa_nn + v];
            u4v wq_nn = *(const u4v*)(Wh + (size_t)q_nn * WHS + grp * 4);

            h2v nev2 = u32_to_h2v(__builtin_amdgcn_perm(ea_c, ea_c, 0x01000100u));
            h2v av2  = u32_to_h2v(__builtin_amdgcn_perm(ea_c, ea_c, 0x03020302u));

            float rd = 0.f;
            #pragma unroll
            for (int j = 0; j < 4; ++j) {
                h2v w2 = u32_to_h2v(wq_c[j]);
#if __has_builtin(__builtin_amdgcn_fdot2)
                rd = __builtin_amdgcn_fdot2(w2, mv4[j], rd, false);
#else
                rd = fmaf((float)w2.x, (float)mv4[j].x,
                     fmaf((float)w2.y, (float)mv4[j].y, rd));
#endif
                mv4[j] = __builtin_elementwise_fma(
                    w2, __builtin_elementwise_fma(nev2, mv4[j], av2), mv4[j]);
            }
            // reduce over the 8 slot-groups (lane stride 8)
            rd += __shfl_xor(rd, 8, 64);
            rd += __shfl_xor(rd, 16, 64);
            rd += __shfl_xor(rd, 32, 64);
            if (grp == 0)
                READ[ro] = f_to_bfu16(rd);
            ro += VD;

            ea_c = ea_n; ea_n = ea_nn;
            wq_c = wq_n; wq_n = wq_nn;
        }
    }
}

// ---- prediction MLP via MFMA: per wave one 16-row strip, K=224, N=64 ----
__global__ __launch_bounds__(256) void mlp_pred(
        const u16* __restrict__ RD, const int* __restrict__ qd,
        const float* __restrict__ Q1tab, const u16* __restrict__ W1s,
        const float* __restrict__ w2, const float* __restrict__ b2,
        float* __restrict__ out) {
    const int tid  = threadIdx.x;
    const int lane = tid & 63;
    const int wv   = tid >> 6;
    const int strip = blockIdx.x * 4 + wv;
    const int row0  = strip * 16;

    const int mrow = lane & 15;        // A row within strip / C-D col (feature)
    const int quad = lane >> 4;

    s8v a[7];
    {
        const u16* arow = RD + (size_t)(row0 + mrow) * VD + quad * 8;
        #pragma unroll
        for (int kt = 0; kt < 7; ++kt)
            a[kt] = *(const s8v*)(arow + kt * 32);   // k>=200 garbage * B=0
    }

    const float b2f = b2[0];
    float pf[4] = {0.f, 0.f, 0.f, 0.f};

    #pragma unroll
    for (int nt = 0; nt < 4; ++nt) {
        s8v bfr[7];
        #pragma unroll
        for (int kt = 0; kt < 7; ++kt)
            bfr[kt] = *(const s8v*)(W1s + (((nt * 7 + kt) * 64) + lane) * 8);

        f4v acc = {0.f, 0.f, 0.f, 0.f};
        #pragma unroll
        for (int kt = 0; kt < 7; ++kt)
            acc = __builtin_amdgcn_mfma_f32_16x16x32_bf16(a[kt], bfr[kt], acc, 0, 0, 0);

        const int f = nt * 16 + mrow;                  // output feature col
        const float w2f = (f < FC) ? w2[f] : 0.f;
        #pragma unroll
        for (int r = 0; r < 4; ++r) {
            int row = row0 + quad * 4 + r;
            float h = acc[r] + Q1tab[qd[row] * FC + f];
            pf[r] = fmaf(fast_tanh(h), w2f, pf[r]);
        }
    }

    #pragma unroll
    for (int r = 0; r < 4; ++r) {
        float s = pf[r];
        s += __shfl_xor(s, 1, 64);
        s += __shfl_xor(s, 2, 64);
        s += __shfl_xor(s, 4, 64);
        s += __shfl_xor(s, 8, 64);
        if (mrow == 0)
            out[row0 + quad * 4 + r] = fast_sigmoid(s + b2f);
    }
}

// ---- fallback (barrier version, f32) if workspace too small ----
__global__ void dkvmn_main(const int* __restrict__ qd, const int* __restrict__ qad,
                           const float* __restrict__ Wtab, const float* __restrict__ Q1tab,
                           const u32* __restrict__ EA,
                           const float* __restrict__ ivm,
                           const float* __restrict__ w1,
                           const float* __restrict__ w2,
                           const float* __restrict__ b2,
                           float* __restrict__ out) {
    const int tid  = threadIdx.x;
    const int b    = blockIdx.x;
    const int v    = tid;
    const int lane = tid & 63;
    const int wv   = tid >> 6;

    __shared__ alignas(16) float read_lds[4 * 52];
    __shared__ alignas(16) float part_lds[4 * 52];

    float mv[MEMN];
    if (v < VD) {
        #pragma unroll
        for (int m = 0; m < MEMN; ++m) mv[m] = ivm[m * VD + v];
    }
    float w1r[50];
    if (lane < FC) {
        #pragma unroll
        for (int i = 0; i < 50; ++i) w1r[i] = w1[(wv * 50 + i) * FC + lane];
    } else {
        #pragma unroll
        for (int i = 0; i < 50; ++i) w1r[i] = 0.f;
    }
    const float w2f = (tid < FC) ? w2[tid] : 0.f;
    const float b2f = b2[0];

    const int* qrow_i  = qd  + b * SS;
    const int* qarow_i = qad + b * SS;
    const int jchunk = v / 50;
    const int wslot  = jchunk * 52 + (v - jchunk * 50);

    for (int t = 0; t < SS; ++t) {
        const int q  = __builtin_amdgcn_readfirstlane(qrow_i[t]);
        const int qa = __builtin_amdgcn_readfirstlane(qarow_i[t]);
        const float* wrow = Wtab + q * MEMN;

        u32 ea = 0;
        if (v < VD) ea = EA[(size_t)qa * VD + v];
        float ne = h16_to_f((u16)(ea & 0xffffu));   // -e
        float av = h16_to_f((u16)(ea >> 16));       //  a

        if (v < VD) {
            float rd0 = 0.f, rd1 = 0.f;
            #pragma unroll
            for (int m = 0; m < MEMN; m += 2) {
                float wm0 = wrow[m], wm1 = wrow[m + 1];
                rd0 = fmaf(wm0, mv[m], rd0);
                mv[m] = fmaf(wm0, fmaf(ne, mv[m], av), mv[m]);
                rd1 = fmaf(wm1, mv[m + 1], rd1);
                mv[m + 1] = fmaf(wm1, fmaf(ne, mv[m + 1], av), mv[m + 1]);
            }
            read_lds[wslot] = rd0 + rd1;
        }
        __syncthreads();

        float part = 0.f;
        {
            const float* rlc = read_lds + wv * 52;
            #pragma unroll
            for (int i = 0; i < 48; i += 4) {
                float4 x = *(const float4*)(rlc + i);
                part = fmaf(x.x, w1r[i],     part);
                part = fmaf(x.y, w1r[i + 1], part);
                part = fmaf(x.z, w1r[i + 2], part);
                part = fmaf(x.w, w1r[i + 3], part);
            }
            part = fmaf(rlc[48], w1r[48], part);
            part = fmaf(rlc[49], w1r[49], part);
        }
        if (lane < FC) part_lds[wv * 52 + lane] = part;
        __syncthreads();

        if (wv == 0) {
            float pf = 0.f;
            if (lane < FC) {
                float h = part_lds[lane] + part_lds[52 + lane] +
                          part_lds[104 + lane] + part_lds[156 + lane] +
                          Q1tab[q * FC + lane];
                pf = fast_tanh(h) * w2f;
            }
            #pragma unroll
            for (int off = 32; off >= 1; off >>= 1) pf += __shfl_xor(pf, off, 64);
            if (lane == 0) out[b * SS + t] = fast_sigmoid(pf + b2f);
        }
    }
}

extern "C" void kernel_launch(void* const* d_in, const int* in_sizes, int n_in,
                              void* d_out, int out_size, void* d_ws, size_t ws_size,
                              hipStream_t stream) {
    const int* qd  = (const int*)d_in[0];
    const int* qad = (const int*)d_in[1];
    const float* qemb  = (const float*)d_in[2];
    const float* qaemb = (const float*)d_in[3];
    const float* km    = (const float*)d_in[4];
    const float* ivm   = (const float*)d_in[5];
    const float* ew    = (const float*)d_in[6];
    const float* eb    = (const float*)d_in[7];
    const float* aw    = (const float*)d_in[8];
    const float* ab    = (const float*)d_in[9];
    const float* w1    = (const float*)d_in[10];
    const float* b1    = (const float*)d_in[11];
    const float* w2    = (const float*)d_in[12];
    const float* b2    = (const float*)d_in[13];
    float* out = (float*)d_out;
    (void)in_sizes; (void)n_in; (void)out_size;

    char* ws = (char*)d_ws;
    float* Wt  = (float*)(ws);                       // 1,000,200 -> pad 1,000,448
    float* Q1  = (float*)(ws + 1000448);             // 1,000,200 -> pad 1,000,448
    u32*   EA  = (u32*)  (ws + 2000896);             // 8,000,800 -> pad 8,001,024
    u16*   W1s = (u16*)  (ws + 10001920);            // 28,672    -> pad 32,768
    u32*   Wh  = (u32*)  (ws + 10034688);            // 640,128   -> pad 640,512
    u16*   RD  = (u16*)  (ws + 10675200);            // 163,840,000
    const size_t need = 10675200ull + 163840000ull + 512ull;

    // prep: EA + Wt/Wh/Q1 + W1s + zero outputs 1..3 (one dispatch)
    prep<<<PREP_G, 256, 0, stream>>>(qemb, km, w1, b1, qaemb, ew, eb, aw, ab,
                                     Wt, Wh, Q1, EA, W1s, out + (size_t)BB * SS);

    if (ws_size >= need) {
        dkvmn_state<<<BB / 4, 1024, 0, stream>>>(qd, qad, Wh, EA, ivm, RD);
        mlp_pred<<<(BB * SS) / 64, 256, 0, stream>>>(RD, qd, Q1, W1s, w2, b2, out);
    } else {
        dkvmn_main<<<BB, 256, 0, stream>>>(qd, qad, Wt, Q1, EA, ivm, w1, w2, b2, out);
    }
}